// Round 5
// baseline (285.178 us; speedup 1.0000x reference)
//
#include <hip/hip_runtime.h>
#include <math.h>

#define NN 10000
#define GG 12
#define CC 64
#define AA 3
#define EE 50000
#define LN_EPS 1e-5f
#define MAXDEG 64   // max in-degree cap; Poisson(E/N=5) max ~17, 64 is far beyond

__device__ __forceinline__ int rfl(int v) { return __builtin_amdgcn_readfirstlane(v); }
__device__ __forceinline__ float bcast_lane(float v, int i) {
    return __uint_as_float(__builtin_amdgcn_readlane(__float_as_uint(v), i));
}

// ---------------- kernel 1: zero per-node counters ----------------
__global__ __launch_bounds__(256) void zero_cnt(int* __restrict__ cnt) {
    int i = blockIdx.x * 256 + threadIdx.x;
    if (i < NN) cnt[i] = 0;
}

// ---------------- kernel 2: bucket edges by destination; pack e | src<<17 ----------------
__global__ __launch_bounds__(256) void bucket_fill(const int* __restrict__ ei,
                                                   int* __restrict__ cnt,
                                                   int* __restrict__ elist) {
    int e = blockIdx.x * 256 + threadIdx.x;
    if (e < EE) {
        int src = ei[e];
        int dst = ei[EE + e];
        int pos = atomicAdd(&cnt[dst], 1);
        if (pos < MAXDEG) elist[dst * MAXDEG + pos] = e | (src << 17);
    }
}

// ---------------- kernel 3: conv gather — attr via VECTOR loads + readlane ----------------
// block = node, 8 waves: wave = (edge-parity ew, g-triple gw); lane = channel.
// Each wave loads the edge's 432-float attr block as 2 coalesced dwordx4
// (floats [0..255] and [176..431] — shifted window keeps the last edge in-bounds),
// then extracts scalars with compile-time v_readlane. Depth-2 software pipeline.
__global__ __launch_bounds__(512, 6) void conv_gather(
    const float* __restrict__ x, const float* __restrict__ attr,
    const float* __restrict__ Wk,
    const int* __restrict__ cnt, const int* __restrict__ elist,
    float* __restrict__ agg) {
    __shared__ float red[4][3][CC];            // 3 KB: edge-parity-1 partials

    const int n    = blockIdx.x;
    const int t    = threadIdx.x;
    const int lane = t & 63;
    const int w    = rfl(t >> 6);
    const int gw   = w & 3;                    // g = gw, gw+4, gw+8
    const int ew   = w >> 2;                   // edge parity 0/1

    const float wk0 = Wk[lane];
    const float wk1 = Wk[CC + lane];
    const float wk2 = Wk[2 * CC + lane];

    float acc[3] = {0.f, 0.f, 0.f};
    const int deg = min(cnt[n], MAXDEG);

    float4 A0c = make_float4(0.f, 0.f, 0.f, 0.f), A1c = A0c;
    float xrc[GG];
    int i = ew;
    if (i < deg) {                             // wave-uniform branch
        const int p = rfl(elist[n * MAXDEG + i]);
        const float* ap = attr + (size_t)(p & 0x1FFFF) * (GG * GG * AA);
        A0c = *(const float4*)(ap + 4 * lane);          // floats 0..255
        A1c = *(const float4*)(ap + 176 + 4 * lane);    // floats 176..431
        const float* xp = x + (p >> 17) * (GG * CC) + lane;
#pragma unroll
        for (int h = 0; h < GG; ++h) xrc[h] = xp[h * CC];
    }

    for (; i < deg; i += 2) {
        // ---- prefetch edge i+2 while computing edge i ----
        float4 A0n = make_float4(0.f, 0.f, 0.f, 0.f), A1n = A0n;
        float xrn[GG];
        if (i + 2 < deg) {
            const int p = rfl(elist[n * MAXDEG + i + 2]);
            const float* ap = attr + (size_t)(p & 0x1FFFF) * (GG * GG * AA);
            A0n = *(const float4*)(ap + 4 * lane);
            A1n = *(const float4*)(ap + 176 + 4 * lane);
            const float* xp = x + (p >> 17) * (GG * CC) + lane;
#pragma unroll
            for (int h = 0; h < GG; ++h) xrn[h] = xp[h * CC];
        } else {
#pragma unroll
            for (int h = 0; h < GG; ++h) xrn[h] = 0.f;
        }

        // ---- compute edge i: attr scalars via compile-time readlane ----
#pragma unroll
        for (int j = 0; j < 3; ++j) {
            const int g = gw + 4 * j;          // gw, so g*36 is not compile-time,
            float t0 = 0.f, t1 = 0.f, t2 = 0.f;
            // but (idx relative selection) must be: handle via runtime-uniform lane idx.
#pragma unroll
            for (int h = 0; h < GG; ++h) {
                const int idx = g * (GG * AA) + h * AA;      // uniform, runtime
                const float xv = xrc[h];
                // select buffer + component; idx%4 alignment: idx = g*36+h*3 -> idx&3 varies
                // component and lane are uniform ints -> readlane with uniform index is legal
                float v0, v1, v2;
                {
                    const int k0 = idx + 0;
                    const int k1 = idx + 1;
                    const int k2 = idx + 2;
                    const float* B0 = (const float*)&A0c;
                    const float* B1 = (const float*)&A1c;
                    v0 = (k0 < 256) ? bcast_lane(B0[k0 & 3], k0 >> 2)
                                    : bcast_lane(B1[(k0 - 176) & 3], (k0 - 176) >> 2);
                    v1 = (k1 < 256) ? bcast_lane(B0[k1 & 3], k1 >> 2)
                                    : bcast_lane(B1[(k1 - 176) & 3], (k1 - 176) >> 2);
                    v2 = (k2 < 256) ? bcast_lane(B0[k2 & 3], k2 >> 2)
                                    : bcast_lane(B1[(k2 - 176) & 3], (k2 - 176) >> 2);
                }
                t0 = fmaf(v0, xv, t0);
                t1 = fmaf(v1, xv, t1);
                t2 = fmaf(v2, xv, t2);
            }
            acc[j] = fmaf(t0, wk0, fmaf(t1, wk1, fmaf(t2, wk2, acc[j])));
        }

        A0c = A0n; A1c = A1n;
#pragma unroll
        for (int h = 0; h < GG; ++h) xrc[h] = xrn[h];
    }

    // ---- cross-parity reduction + store ----
    if (ew == 1) {
#pragma unroll
        for (int j = 0; j < 3; ++j) red[gw][j][lane] = acc[j];
    }
    __syncthreads();
    if (ew == 0) {
#pragma unroll
        for (int j = 0; j < 3; ++j)
            agg[(n * GG + gw + 4 * j) * CC + lane] = acc[j] + red[gw][j][lane];
    }
}

// ---------------- kernel 4: LN + MLP(GELU) + layer_scale + residual ----------------
__device__ __forceinline__ float bl(float v, int i) {
    return __uint_as_float(__builtin_amdgcn_readlane(__float_as_uint(v), i));
}

__global__ __launch_bounds__(256, 2) void ln_mlp(
    const float* __restrict__ x, const float* __restrict__ cb,
    const float* __restrict__ lnw, const float* __restrict__ lnb,
    const float* __restrict__ W1, const float* __restrict__ b1,
    const float* __restrict__ W2, const float* __restrict__ b2,
    const float* __restrict__ ls, float* __restrict__ out) {
    const int lane = threadIdx.x & 63;
    const int wv   = threadIdx.x >> 6;

    float w1r[CC], w2r[CC];
#pragma unroll
    for (int i = 0; i < CC; ++i) {
        w1r[i] = W1[i * CC + lane];
        w2r[i] = W2[i * CC + lane];
    }
    const float cbv = cb[lane];
    const float lw  = lnw[lane], lb = lnb[lane];
    const float bb1 = b1[lane],  bb2 = b2[lane];
    const float lsc = ls[lane];

    const int nf = NN * GG;
    const int nw = gridDim.x * 4;
    for (int f = blockIdx.x * 4 + wv; f < nf; f += nw) {
        const float v = out[f * CC + lane] + cbv;   // agg written here by conv_gather
        float s = v, s2 = v * v;
#pragma unroll
        for (int off = 32; off; off >>= 1) {
            s  += __shfl_xor(s,  off);
            s2 += __shfl_xor(s2, off);
        }
        const float mu  = s * (1.f / 64.f);
        const float var = s2 * (1.f / 64.f) - mu * mu;
        const float hh  = (v - mu) * rsqrtf(var + LN_EPS) * lw + lb;

        float a0 = 0.f, a1 = 0.f, a2 = 0.f, a3 = 0.f;
#pragma unroll
        for (int i = 0; i < CC; i += 4) {
            a0 = fmaf(bl(hh, i),     w1r[i],     a0);
            a1 = fmaf(bl(hh, i + 1), w1r[i + 1], a1);
            a2 = fmaf(bl(hh, i + 2), w1r[i + 2], a2);
            a3 = fmaf(bl(hh, i + 3), w1r[i + 3], a3);
        }
        const float z  = ((a0 + a1) + (a2 + a3)) + bb1;
        const float gl = 0.5f * z * (1.f + erff(z * 0.70710678118654752f));

        float c0 = 0.f, c1 = 0.f, c2 = 0.f, c3 = 0.f;
#pragma unroll
        for (int i = 0; i < CC; i += 4) {
            c0 = fmaf(bl(gl, i),     w2r[i],     c0);
            c1 = fmaf(bl(gl, i + 1), w2r[i + 1], c1);
            c2 = fmaf(bl(gl, i + 2), w2r[i + 2], c2);
            c3 = fmaf(bl(gl, i + 3), w2r[i + 3], c3);
        }
        const float z2 = ((c0 + c1) + (c2 + c3)) + bb2;

        out[f * CC + lane] = fmaf(lsc, z2, x[f * CC + lane]);
    }
}

extern "C" void kernel_launch(void* const* d_in, const int* in_sizes, int n_in,
                              void* d_out, int out_size, void* d_ws, size_t ws_size,
                              hipStream_t stream) {
    const float* x    = (const float*)d_in[0];
    const float* attr = (const float*)d_in[1];
    const float* Wk   = (const float*)d_in[2];
    const float* cb   = (const float*)d_in[3];
    const float* lnw  = (const float*)d_in[4];
    const float* lnb  = (const float*)d_in[5];
    const float* W1   = (const float*)d_in[6];
    const float* b1   = (const float*)d_in[7];
    const float* W2   = (const float*)d_in[8];
    const float* b2   = (const float*)d_in[9];
    const float* ls   = (const float*)d_in[10];
    const int*   ei   = (const int*)d_in[11];
    float* out = (float*)d_out;

    int* cnt   = (int*)d_ws;            // NN ints
    int* elist = cnt + NN;              // NN*MAXDEG ints (2.56 MB)

    zero_cnt<<<(NN + 255) / 256, 256, 0, stream>>>(cnt);
    bucket_fill<<<(EE + 255) / 256, 256, 0, stream>>>(ei, cnt, elist);
    conv_gather<<<NN, 512, 0, stream>>>(x, attr, Wk, cnt, elist, out);
    ln_mlp<<<512, 256, 0, stream>>>(x, cb, lnw, lnb, W1, b1, W2, b2, ls, out);
}